// Round 5
// baseline (158.761 us; speedup 1.0000x reference)
//
#include <hip/hip_runtime.h>
#include <hip/hip_bf16.h>
#include <math.h>

// MyAttentionHead: B=4, S=2048, d_model=1024, d_head=64. fp32 in/out storage.
// out = ((P~ @ xv) * 1/l) @ O^T  with FUSED flash attention + output GEMM:
// K0 wprep (QKV hi/lo transposed + O hi/lo), K1a qkv_part MFMA (K-split 4),
// K1b qkv_reduce (+xv PERMUTED to MFMA-B-fragment order xvP),
// K2 attn_out: S^T=mfma(K,Q) -> exp -> in-register P frag -> PV mfma ->
//    cross-wave O/l combine in LDS -> EPILOGUE GEMM vs O^T -> fp32 out.
//    (paired 16-row q-tiles (j,127-j): 33-34 uniform 64k-chunks/block;
//     epilogue: each of 8 waves owns a 128-col e-slice, 96 MFMA.)
#define BATCH 4
#define SEQ   2048
#define DM    1024
#define DH    64
#define NROWS (BATCH*SEQ)   // 8192

typedef __hip_bfloat16 bf16;
typedef __attribute__((ext_vector_type(8))) short short8;
typedef __attribute__((ext_vector_type(8))) unsigned short ushortx8;
typedef __attribute__((ext_vector_type(4))) float floatx4;

__device__ __forceinline__ ushort f2bf(float f) {
    union { bf16 h; ushort u; } cv;
    cv.h = __float2bfloat16(f);
    return cv.u;
}
__device__ __forceinline__ float bf2f(ushort u) {
    union { unsigned int i; float f; } v; v.i = ((unsigned int)u) << 16; return v.f;
}

// ---------------- K0: weight prep ----------------
__global__ __launch_bounds__(256) void wprep_kernel(
    const float* __restrict__ Q, const float* __restrict__ K,
    const float* __restrict__ V, const float* __restrict__ O,
    ushort* __restrict__ WhT, ushort* __restrict__ WlT,
    ushort* __restrict__ Oh, ushort* __restrict__ Ol)
{
    int n = blockIdx.x;                       // 0..255
    if (n < 192) {
        const float* W = (n < 64) ? Q : (n < 128) ? K : V;
        int c = n & 63;
        for (int k = threadIdx.x; k < DM; k += 256) {
            float w = W[k * DH + c];
            ushort hi = f2bf(w);
            WhT[n * DM + k] = hi;
            WlT[n * DM + k] = f2bf(w - bf2f(hi));
        }
    } else {
        int e0 = (n - 192) << 4;              // 16 rows of O per block
        for (int idx = threadIdx.x; idx < 16 * DH; idx += 256) {
            int off = (e0 << 6) + idx;
            float w = O[off];
            ushort hi = f2bf(w);
            Oh[off] = hi;
            Ol[off] = f2bf(w - bf2f(hi));
        }
    }
}

// ---------------- K1a: qkv partial MFMA (K-split 4) ----------------
__global__ __launch_bounds__(256) void qkv_part_kernel(
    const float* __restrict__ x, const ushort* __restrict__ WhT,
    const ushort* __restrict__ WlT, float* __restrict__ Cpart)
{
    __shared__ __align__(16) ushort Xs[2][32][34];
    __shared__ __align__(16) ushort Ws[2][192][34];
    int s0 = blockIdx.x * 32;
    int kb = blockIdx.y * 256;
    int t = threadIdx.x;
    int wave = t >> 6, lane = t & 63, m_ = lane & 15, qd = lane >> 4;
    const floatx4 z4 = {0.f, 0.f, 0.f, 0.f};
    floatx4 accq[2] = {z4, z4}, acck[2] = {z4, z4}, accv[2] = {z4, z4};
    int xr = t >> 3, xc = (t & 7) * 4;
    for (int k0 = 0; k0 < 256; k0 += 32) {
        float4 v = *(const float4*)&x[(size_t)(s0 + xr) * DM + kb + k0 + xc];
        ushort h0 = f2bf(v.x), h1 = f2bf(v.y), h2 = f2bf(v.z), h3 = f2bf(v.w);
        *(ushort4*)&Xs[0][xr][xc] = make_ushort4(h0, h1, h2, h3);
        *(ushort4*)&Xs[1][xr][xc] = make_ushort4(
            f2bf(v.x - bf2f(h0)), f2bf(v.y - bf2f(h1)),
            f2bf(v.z - bf2f(h2)), f2bf(v.w - bf2f(h3)));
        #pragma unroll
        for (int j = 0; j < 3; ++j) {
            int idx = t + j * 256, n = idx >> 2, kc = (idx & 3) * 8;
            *(uint4*)&Ws[0][n][kc] = *(const uint4*)&WhT[n * DM + kb + k0 + kc];
            *(uint4*)&Ws[1][n][kc] = *(const uint4*)&WlT[n * DM + kb + k0 + kc];
        }
        __syncthreads();
        short8 ah[2], al[2];
        #pragma unroll
        for (int mi = 0; mi < 2; ++mi) {
            ah[mi] = *(const short8*)&Xs[0][mi * 16 + m_][qd * 8];
            al[mi] = *(const short8*)&Xs[1][mi * 16 + m_][qd * 8];
        }
        int nq = wave * 16 + m_, nk = 64 + wave * 16 + m_, nv = 128 + wave * 16 + m_;
        short8 bqh = *(const short8*)&Ws[0][nq][qd * 8];
        short8 bql = *(const short8*)&Ws[1][nq][qd * 8];
        short8 bkh = *(const short8*)&Ws[0][nk][qd * 8];
        short8 bkl = *(const short8*)&Ws[1][nk][qd * 8];
        short8 bvh = *(const short8*)&Ws[0][nv][qd * 8];
        #pragma unroll
        for (int mi = 0; mi < 2; ++mi) {
            accq[mi] = __builtin_amdgcn_mfma_f32_16x16x32_bf16(ah[mi], bqh, accq[mi], 0, 0, 0);
            accq[mi] = __builtin_amdgcn_mfma_f32_16x16x32_bf16(al[mi], bqh, accq[mi], 0, 0, 0);
            accq[mi] = __builtin_amdgcn_mfma_f32_16x16x32_bf16(ah[mi], bql, accq[mi], 0, 0, 0);
            acck[mi] = __builtin_amdgcn_mfma_f32_16x16x32_bf16(ah[mi], bkh, acck[mi], 0, 0, 0);
            acck[mi] = __builtin_amdgcn_mfma_f32_16x16x32_bf16(al[mi], bkh, acck[mi], 0, 0, 0);
            acck[mi] = __builtin_amdgcn_mfma_f32_16x16x32_bf16(ah[mi], bkl, acck[mi], 0, 0, 0);
            accv[mi] = __builtin_amdgcn_mfma_f32_16x16x32_bf16(ah[mi], bvh, accv[mi], 0, 0, 0);
        }
        __syncthreads();
    }
    float* Cp = Cpart + (size_t)blockIdx.y * (NROWS * 192);
    #pragma unroll
    for (int mi = 0; mi < 2; ++mi) {
        #pragma unroll
        for (int r = 0; r < 4; ++r) {
            int row = s0 + mi * 16 + qd * 4 + r;
            float* base = Cp + (size_t)row * 192;
            base[wave * 16 + m_]       = accq[mi][r];
            base[64 + wave * 16 + m_]  = acck[mi][r];
            base[128 + wave * 16 + m_] = accv[mi][r];
        }
    }
}

// ---------------- K1b: reduce partials, split hi/lo, permute xv ----------------
// 32 rows (= one 32-k chunk) per block. xvP layout [b][c32][qd][h][j]:
// element = xv[k = c32*32 + 16*(j>>2) + 4*qd + (j&3)][h]  (MFMA B-frag order).
__global__ __launch_bounds__(256) void qkv_reduce_kernel(
    const float* __restrict__ Cpart,
    ushort* __restrict__ qh, ushort* __restrict__ ql,
    ushort* __restrict__ kh, ushort* __restrict__ kl, ushort* __restrict__ xvP)
{
    __shared__ ushort xvs[32][72];
    const size_t SL = (size_t)NROWS * 192;
    int row0 = blockIdx.x * 32;
    int t = threadIdx.x;
    #pragma unroll
    for (int i = 0; i < 24; ++i) {
        int e = i * 256 + t;
        int r = e / 192, c = e - r * 192;
        size_t row = row0 + r;
        size_t off = row * 192 + c;
        float s = Cpart[off] + Cpart[SL + off] + Cpart[2 * SL + off] + Cpart[3 * SL + off];
        ushort hi = f2bf(s);
        if (c < 64) {
            qh[row * 64 + c] = hi; ql[row * 64 + c] = f2bf(s - bf2f(hi));
        } else if (c < 128) {
            kh[row * 64 + c - 64] = hi; kl[row * 64 + c - 64] = f2bf(s - bf2f(hi));
        } else {
            xvs[r][c - 128] = hi;
        }
    }
    __syncthreads();
    int h = t & 63, qd = t >> 6;          // 4 waves <-> qd 0..3
    ushortx8 v;
    #pragma unroll
    for (int j = 0; j < 8; ++j)
        v[j] = xvs[4 * qd + (j & 3) + ((j >> 2) << 4)][h];
    int b = row0 >> 11, c32 = (row0 & 2047) >> 5;
    *(ushortx8*)&xvP[((((size_t)b << 6) + c32) * 4 + qd) * 512 + h * 8] = v;
}

// ---------------- K2: fused attention + output GEMM ----------------
// Block = (pair pp, batch b): q-tiles jA=pp, jB=127-pp (16 rows each).
// 8 waves share the combined 64k-chunk list (nA+nB = 33/34, uniform).
// Per chunk: S^T = mfma(K,Q) hi/lo; mask+exp -> bf16 P A-frag in-register
// (k-order perm matches xvP); PV mfma. Then cross-wave O/l combine in LDS,
// and epilogue GEMM: out[rows] = (Axv * 1/l) @ O^T, each wave a 128-col slice.
__global__ __launch_bounds__(512) void attn_kernel(
    const ushort* __restrict__ qh, const ushort* __restrict__ ql,
    const ushort* __restrict__ kh, const ushort* __restrict__ kl,
    const ushort* __restrict__ xvP,
    const ushort* __restrict__ Oh, const ushort* __restrict__ Ol,
    float* __restrict__ out)
{
    __shared__ __align__(16) ushort Qs[2][2][16][72];  // [tile][hi/lo][row][col]
    __shared__ float LO[2][2][16][68];                 // [wavepart][tile][q][h]
    __shared__ float lred[8][2][16];                   // [wave][tile][q]
    __shared__ float lsc[2][16];
    int pp = blockIdx.x & 63, b = blockIdx.x >> 6;
    int srowA = pp << 4, srowB = (127 - pp) << 4;
    int t = threadIdx.x, wave = t >> 6, lane = t & 63, m_ = lane & 15, qd = lane >> 4;
    {   // stage Q tiles: 512 threads x 1 uint4
        int tile = t >> 8, hl = (t >> 7) & 1, r = (t >> 3) & 15, c = (t & 7) * 8;
        const ushort* src = (hl ? ql : qh) + (size_t)((b << 11) + (tile ? srowB : srowA) + r) * 64 + c;
        *(uint4*)&Qs[tile][hl][r][c] = *(const uint4*)src;
    }
    __syncthreads();
    int nA = (pp >> 2) + 1, nB = ((127 - pp) >> 2) + 1;
    int M = nA + nB;
    const ushort* khb = kh + (((size_t)b << 11)) * 64;
    const ushort* klb = kl + (((size_t)b << 11)) * 64;
    const ushort* xvb = xvP + ((size_t)b << 17);       // 64*4*64*8 per batch
    const floatx4 z4 = {0.f, 0.f, 0.f, 0.f};
    floatx4 accOA[4] = {z4, z4, z4, z4};
    floatx4 accOB[4] = {z4, z4, z4, z4};
    float llA = 0.f, llB = 0.f;
    for (int it = wave; it < M; it += 8) {
        int tile = (it >= nA);
        int c = tile ? (it - nA) : it;
        int srow = tile ? srowB : srowA;
        int k0 = c << 6;
        floatx4 accS[4] = {z4, z4, z4, z4};
        #pragma unroll
        for (int kk = 0; kk < 2; ++kk) {
            short8 bqh, bql;
            if (tile == 0) {
                bqh = *(const short8*)&Qs[0][0][m_][kk * 32 + qd * 8];
                bql = *(const short8*)&Qs[0][1][m_][kk * 32 + qd * 8];
            } else {
                bqh = *(const short8*)&Qs[1][0][m_][kk * 32 + qd * 8];
                bql = *(const short8*)&Qs[1][1][m_][kk * 32 + qd * 8];
            }
            #pragma unroll
            for (int mt = 0; mt < 4; ++mt) {
                size_t koff = (size_t)(k0 + mt * 16 + m_) * 64 + kk * 32 + qd * 8;
                short8 akh = *(const short8*)&khb[koff];
                short8 akl = *(const short8*)&klb[koff];
                accS[mt] = __builtin_amdgcn_mfma_f32_16x16x32_bf16(akh, bqh, accS[mt], 0, 0, 0);
                accS[mt] = __builtin_amdgcn_mfma_f32_16x16x32_bf16(akl, bqh, accS[mt], 0, 0, 0);
                accS[mt] = __builtin_amdgcn_mfma_f32_16x16x32_bf16(akh, bql, accS[mt], 0, 0, 0);
            }
        }
        int qrow = srow + m_;
        float lsum = 0.f;
        short8 pa[2];
        #pragma unroll
        for (int h2 = 0; h2 < 2; ++h2) {
            #pragma unroll
            for (int tt = 0; tt < 2; ++tt) {
                int mt = h2 * 2 + tt;
                #pragma unroll
                for (int r = 0; r < 4; ++r) {
                    int kc = k0 + mt * 16 + qd * 4 + r;
                    float p = (kc <= qrow) ? __expf(accS[mt][r]) : 0.f;
                    lsum += p;
                    pa[h2][tt * 4 + r] = (short)f2bf(p);
                }
            }
        }
        if (tile == 0) llA += lsum; else llB += lsum;
        #pragma unroll
        for (int h2 = 0; h2 < 2; ++h2) {
            int c32 = (k0 >> 5) + h2;
            const ushort* xb = xvb + ((size_t)c32 * 4 + qd) * 512 + m_ * 8;
            short8 x0 = *(const short8*)&xb[0];
            short8 x1 = *(const short8*)&xb[128];
            short8 x2 = *(const short8*)&xb[256];
            short8 x3 = *(const short8*)&xb[384];
            if (tile == 0) {
                accOA[0] = __builtin_amdgcn_mfma_f32_16x16x32_bf16(pa[h2], x0, accOA[0], 0, 0, 0);
                accOA[1] = __builtin_amdgcn_mfma_f32_16x16x32_bf16(pa[h2], x1, accOA[1], 0, 0, 0);
                accOA[2] = __builtin_amdgcn_mfma_f32_16x16x32_bf16(pa[h2], x2, accOA[2], 0, 0, 0);
                accOA[3] = __builtin_amdgcn_mfma_f32_16x16x32_bf16(pa[h2], x3, accOA[3], 0, 0, 0);
            } else {
                accOB[0] = __builtin_amdgcn_mfma_f32_16x16x32_bf16(pa[h2], x0, accOB[0], 0, 0, 0);
                accOB[1] = __builtin_amdgcn_mfma_f32_16x16x32_bf16(pa[h2], x1, accOB[1], 0, 0, 0);
                accOB[2] = __builtin_amdgcn_mfma_f32_16x16x32_bf16(pa[h2], x2, accOB[2], 0, 0, 0);
                accOB[3] = __builtin_amdgcn_mfma_f32_16x16x32_bf16(pa[h2], x3, accOB[3], 0, 0, 0);
            }
        }
    }
    // l: reduce over qd lanes -> full partial for q=m_
    llA += __shfl_xor(llA, 16); llA += __shfl_xor(llA, 32);
    llB += __shfl_xor(llB, 16); llB += __shfl_xor(llB, 32);
    if (qd == 0) { lred[wave][0][m_] = llA; lred[wave][1][m_] = llB; }
    // O: cross-wave combine (waves 0-3 -> part 0, waves 4-7 -> part 1)
    int part = wave >> 2, w4 = wave & 3;
    for (int w = 0; w < 4; ++w) {
        if (w4 == w) {
            #pragma unroll
            for (int hn = 0; hn < 4; ++hn)
                #pragma unroll
                for (int r = 0; r < 4; ++r) {
                    int q = qd * 4 + r, h = hn * 16 + m_;
                    if (w == 0) {
                        LO[part][0][q][h] = accOA[hn][r];
                        LO[part][1][q][h] = accOB[hn][r];
                    } else {
                        LO[part][0][q][h] += accOA[hn][r];
                        LO[part][1][q][h] += accOB[hn][r];
                    }
                }
        }
        __syncthreads();
    }
    // 1/l per (tile, q)
    if (t < 32) {
        int tile = t >> 4, q = t & 15;
        float lt = 0.f;
        #pragma unroll
        for (int w = 0; w < 8; ++w) lt += lred[w][tile][q];
        lsc[tile][q] = 1.f / lt;
    }
    __syncthreads();
    // ---------- epilogue GEMM: out[rows] = Axv @ O^T, wave owns 128 e-cols ----------
    int e0w = wave << 7;
    short8 Ah[2][2], Al[2][2];
    #pragma unroll
    for (int tile = 0; tile < 2; ++tile) {
        float sc = lsc[tile][m_];
        #pragma unroll
        for (int kk = 0; kk < 2; ++kk) {
            #pragma unroll
            for (int j = 0; j < 8; ++j) {
                int h = kk * 32 + qd * 8 + j;
                float v = (LO[0][tile][m_][h] + LO[1][tile][m_][h]) * sc;
                ushort hv = f2bf(v);
                Ah[tile][kk][j] = (short)hv;
                Al[tile][kk][j] = (short)f2bf(v - bf2f(hv));
            }
        }
    }
    floatx4 accE[2][8];
    #pragma unroll
    for (int tile = 0; tile < 2; ++tile)
        #pragma unroll
        for (int ni = 0; ni < 8; ++ni) accE[tile][ni] = z4;
    #pragma unroll
    for (int ni = 0; ni < 8; ++ni) {
        #pragma unroll
        for (int kk = 0; kk < 2; ++kk) {
            size_t boff = (size_t)(e0w + ni * 16 + m_) * 64 + kk * 32 + qd * 8;
            short8 bh = *(const short8*)&Oh[boff];
            short8 bl = *(const short8*)&Ol[boff];
            #pragma unroll
            for (int tile = 0; tile < 2; ++tile) {
                accE[tile][ni] = __builtin_amdgcn_mfma_f32_16x16x32_bf16(Ah[tile][kk], bh, accE[tile][ni], 0, 0, 0);
                accE[tile][ni] = __builtin_amdgcn_mfma_f32_16x16x32_bf16(Al[tile][kk], bh, accE[tile][ni], 0, 0, 0);
                accE[tile][ni] = __builtin_amdgcn_mfma_f32_16x16x32_bf16(Ah[tile][kk], bl, accE[tile][ni], 0, 0, 0);
            }
        }
    }
    float* ob = out + ((size_t)b * SEQ) * DM;
    #pragma unroll
    for (int tile = 0; tile < 2; ++tile) {
        int srow = tile ? srowB : srowA;
        #pragma unroll
        for (int r = 0; r < 4; ++r) {
            float* orow = ob + (size_t)(srow + qd * 4 + r) * DM + e0w;
            #pragma unroll
            for (int ni = 0; ni < 8; ++ni)
                orow[ni * 16 + m_] = accE[tile][ni][r];
        }
    }
}

extern "C" void kernel_launch(void* const* d_in, const int* in_sizes, int n_in,
                              void* d_out, int out_size, void* d_ws, size_t ws_size,
                              hipStream_t stream) {
    const float* x = (const float*)d_in[0];
    const float* Q = (const float*)d_in[1];
    const float* K = (const float*)d_in[2];
    const float* V = (const float*)d_in[3];
    const float* O = (const float*)d_in[4];
    float* out = (float*)d_out;

    char* ws = (char*)d_ws;
    ushort* qh   = (ushort*)(ws);                    // 1 MB [8192][64] bf16
    ushort* ql   = (ushort*)(ws + (1ull  << 20));
    ushort* kh   = (ushort*)(ws + (2ull  << 20));
    ushort* kl   = (ushort*)(ws + (3ull  << 20));
    ushort* xvP  = (ushort*)(ws + (4ull  << 20));    // 1 MB [4][64][4][64][8] permuted xv
    ushort* WhT  = (ushort*)(ws + (5ull  << 20));    // 384 KB [192][1024]
    ushort* WlT  = (ushort*)(ws + (5ull  << 20) + (512ull << 10));
    ushort* Oh   = (ushort*)(ws + (6ull  << 20));                   // 128 KB [1024][64]
    ushort* Ol   = (ushort*)(ws + (6ull  << 20) + (128ull << 10));  // 128 KB
    float*  Cpart = (float*)(ws + (23ull << 20));    // 25 MB [4][8192][192]

    wprep_kernel<<<256, 256, 0, stream>>>(Q, K, V, O, WhT, WlT, Oh, Ol);
    qkv_part_kernel<<<dim3(NROWS / 32, 4), 256, 0, stream>>>(x, WhT, WlT, Cpart);
    qkv_reduce_kernel<<<NROWS / 32, 256, 0, stream>>>(Cpart, qh, ql, kh, kl, xvP);
    attn_kernel<<<64 * BATCH, 512, 0, stream>>>(qh, ql, kh, kl, xvP, Oh, Ol, out);
}